// Round 5
// baseline (19624.493 us; speedup 1.0000x reference)
//
#include <hip/hip_runtime.h>
#include <stdint.h>

#define T_SEQ 1024
#define BATCH 32
#define HD    512
#define G3    1536   // 3*HD
#define RS    32     // blocks per direction in scan

typedef __attribute__((ext_vector_type(8))) short bf16x8;
typedef __attribute__((ext_vector_type(4))) float f32x4;
typedef __attribute__((ext_vector_type(4))) unsigned short us4;
typedef __attribute__((ext_vector_type(8))) unsigned short us8;

__device__ __forceinline__ float bf2f(unsigned short u) {
    unsigned int v = ((unsigned int)u) << 16;
    float f; __builtin_memcpy(&f, &v, 4); return f;
}
__device__ __forceinline__ unsigned short f2bf(float f) {
    unsigned int u; __builtin_memcpy(&u, &f, 4);
    unsigned int r = ((u >> 16) & 1u) + 0x7FFFu;
    return (unsigned short)((u + r) >> 16);
}
__device__ __forceinline__ float fsig(float x)  { return 1.f / (1.f + __expf(-x)); }
__device__ __forceinline__ float ftanh(float x) { return 1.f - 2.f / (__expf(2.f * x) + 1.f); }

// load 8 consecutive elements as bf16 (converting from fp32 if needed)
template<typename T> __device__ __forceinline__ us8 load8(const T* p);
template<> __device__ __forceinline__ us8 load8<unsigned short>(const unsigned short* p) {
    return *(const us8*)p;
}
template<> __device__ __forceinline__ us8 load8<float>(const float* p) {
    f32x4 a = *(const f32x4*)p;
    f32x4 b = *(const f32x4*)(p + 4);
    us8 r;
    r[0]=f2bf(a[0]); r[1]=f2bf(a[1]); r[2]=f2bf(a[2]); r[3]=f2bf(a[3]);
    r[4]=f2bf(b[0]); r[5]=f2bf(b[1]); r[6]=f2bf(b[2]); r[7]=f2bf(b[3]);
    return r;
}

// store a float as output element type
template<typename T> __device__ __forceinline__ T stoT(float f);
template<> __device__ __forceinline__ unsigned short stoT<unsigned short>(float f) { return f2bf(f); }
template<> __device__ __forceinline__ float stoT<float>(float f) { return f; }

// ---------------------------------------------------------------------------
// Chunked gi GEMM (bf16 MFMA, fp32 acc, bf16 gi output):
//   gi[dir][lt][g][b] = sum_k A[rowBase_dir + lt*32 + b][k] * W[g][k] + bih[g]
// A: [T*32][K] (fp32 for layer 0 input x, bf16 for internal activations).
// W,b: fp32 (harness inputs). grid (12, TC*32/128, 2), block 256.
// ---------------------------------------------------------------------------
template<typename AT>
__global__ __launch_bounds__(256) void gi_gemm(
    const AT* __restrict__ A, int K, int rowBase0, int rowBase1,
    const float* __restrict__ W0, const float* __restrict__ W1,
    const float* __restrict__ b0, const float* __restrict__ b1,
    unsigned short* __restrict__ gi, int TC)
{
    const int dir = blockIdx.z;
    const int rowBase = dir ? rowBase1 : rowBase0;
    const float* W    = dir ? W1 : W0;
    const float* bias = dir ? b1 : b0;
    unsigned short* giD = gi + (size_t)dir * TC * G3 * BATCH;

    const int bm = blockIdx.y * 128;
    const int bn = blockIdx.x * 128;

    __shared__ __attribute__((aligned(16))) unsigned short As[128][40];
    __shared__ __attribute__((aligned(16))) unsigned short Bs[128][40];

    const int tid  = threadIdx.x;
    const int lane = tid & 63;
    const int wave = tid >> 6;
    const int wm = (wave & 1) * 64;
    const int wn = (wave >> 1) * 64;

    f32x4 acc[4][4];
    const f32x4 zz = {0.f, 0.f, 0.f, 0.f};
    #pragma unroll
    for (int i = 0; i < 4; i++)
        #pragma unroll
        for (int j = 0; j < 4; j++) acc[i][j] = zz;

    const int sc = (tid & 3) * 8;
    const int sr = tid >> 2;

    const int kIters = K >> 5;
    for (int kb = 0; kb < kIters; ++kb) {
        const int k0 = kb * 32;
        #pragma unroll
        for (int p = 0; p < 2; ++p) {
            const int row = sr + p * 64;
            *(us8*)(&As[row][sc]) = load8<AT>(A + (size_t)(rowBase + bm + row) * K + k0 + sc);
            *(us8*)(&Bs[row][sc]) = load8<float>(W + (size_t)(bn + row) * K + k0 + sc);
        }
        __syncthreads();
        bf16x8 af[4], bfr[4];
        #pragma unroll
        for (int i = 0; i < 4; i++) {
            af[i]  = *(const bf16x8*)(&As[wm + i * 16 + (lane & 15)][(lane >> 4) * 8]);
            bfr[i] = *(const bf16x8*)(&Bs[wn + i * 16 + (lane & 15)][(lane >> 4) * 8]);
        }
        #pragma unroll
        for (int i = 0; i < 4; i++)
            #pragma unroll
            for (int j = 0; j < 4; j++)
                acc[i][j] = __builtin_amdgcn_mfma_f32_16x16x32_bf16(af[i], bfr[j], acc[i][j], 0, 0, 0);
        __syncthreads();
    }

    #pragma unroll
    for (int j = 0; j < 4; j++) {
        const int g = bn + wn + j * 16 + (lane & 15);
        const float bv = bias[g];
        #pragma unroll
        for (int i = 0; i < 4; i++) {
            const int m  = bm + wm + i * 16 + ((lane >> 4) * 4);
            const int lt = m >> 5;
            const int bb = m & 31;
            us4 o;
            #pragma unroll
            for (int q = 0; q < 4; q++) o[q] = f2bf(acc[i][j][q] + bv);
            *(us4*)(giD + ((size_t)lt * G3 + g) * BATCH + bb) = o;
        }
    }
}

// ---------------------------------------------------------------------------
// Persistent GRU scan for TC steps (chunk c of nc). 64 blocks x 128 threads.
// dir = blk>>5. Block owns 16 hidden cols; Whh slice (48x512) LDS-resident
// (fp32 source converted to bf16); h exchange via double-buffered global hbuf
// (bf16) + fp32 persistence. dst element type DT (bf16 scratch / fp32 final);
// finals always fp32.
// ---------------------------------------------------------------------------
template<typename DT>
__global__ __launch_bounds__(128) void gru_scan(
    const unsigned short* __restrict__ gi,     // [2][TC][G3][B] bf16
    const float* Wf, const float* Wb, const float* bhf, const float* bhb,
    const float* __restrict__ h0l,             // layer base: [2][32][512] fp32
    DT* __restrict__ dst,                      // [T][B][1024]
    float* __restrict__ finals,                // layer base: [2][32][512] fp32
    unsigned short* __restrict__ hbuf,         // [2 dir][2 par][32][512] bf16
    float* __restrict__ hf32,                  // [2 dir][32][512] fp32
    unsigned int* __restrict__ cnt,            // chunk base: [2 dir] x 64
    int c, int TC, int nc)
{
    const int blk   = blockIdx.x;
    const int dir   = blk >> 5;
    const int sl    = blk & 31;
    const int jbase = sl * 16;

    const float* W   = dir ? Wb  : Wf;
    const float* bhh = dir ? bhb : bhf;
    const unsigned short* giD = gi + (size_t)dir * TC * G3 * BATCH;
    unsigned short* hb = hbuf + (size_t)dir * 2 * BATCH * HD;
    float* hfd = hf32 + (size_t)dir * BATCH * HD;
    unsigned int* cc = cnt + (size_t)dir * 64;

    const int tid  = threadIdx.x;
    const int lane = tid & 63;
    const int wave = tid >> 6;      // batches 0-15 / 16-31
    const int jj   = lane & 15;
    const int quad = lane >> 4;
    const int j    = jbase + jj;

    __shared__ __attribute__((aligned(16))) unsigned short wlds[48 * 520];

    for (int idx = tid; idx < 48 * 64; idx += 128) {
        const int r   = idx >> 6;
        const int ch  = (idx & 63) * 8;
        const int q   = r >> 4;
        const int rr  = r & 15;
        *(us8*)(&wlds[r * 520 + ch]) = load8<float>(W + (size_t)(q * HD + jbase + rr) * HD + ch);
    }

    const int bb = wave * 16 + quad * 4;        // C-layout batch base
    float hown[4];
    if (c == 0) {
        const float* h0d = h0l + (size_t)dir * BATCH * HD;
        #pragma unroll
        for (int i = 0; i < 4; i++) hown[i] = h0d[(size_t)(bb + i) * HD + j];
    } else {
        #pragma unroll
        for (int i = 0; i < 4; i++) hown[i] = hfd[(size_t)(bb + i) * HD + j];
    }

    const float bh_r = bhh[0 * HD + j];
    const float bh_z = bhh[1 * HD + j];
    const float bh_n = bhh[2 * HD + j];

    #pragma unroll
    for (int i = 0; i < 4; i++) hb[(size_t)(bb + i) * HD + j] = f2bf(hown[i]);
    __syncthreads();
    if (tid == 0) {
        __builtin_amdgcn_fence(__ATOMIC_RELEASE, "agent");
        __hip_atomic_fetch_add(cc, 1u, __ATOMIC_RELAXED, __HIP_MEMORY_SCOPE_AGENT);
    }

    const int arow = wave * 16 + (lane & 15);   // MFMA A row (batch)
    for (int ls = 0; ls < TC; ++ls) {
        const int s  = c * TC + ls;
        const int t  = dir ? (T_SEQ - 1 - s) : s;
        const int lt = dir ? (TC - 1 - ls) : ls;

        const size_t gb = (size_t)lt * G3 * BATCH;
        const us4 gr = *(const us4*)(giD + gb + (size_t)(0 * HD + j) * BATCH + bb);
        const us4 gz = *(const us4*)(giD + gb + (size_t)(1 * HD + j) * BATCH + bb);
        const us4 gn = *(const us4*)(giD + gb + (size_t)(2 * HD + j) * BATCH + bb);

        if (tid == 0) {
            const unsigned int target = (unsigned int)RS * (unsigned int)(ls + 1);
            while (__hip_atomic_load(cc, __ATOMIC_RELAXED, __HIP_MEMORY_SCOPE_AGENT) < target)
                __builtin_amdgcn_s_sleep(1);
            __builtin_amdgcn_fence(__ATOMIC_ACQUIRE, "agent");
        }
        __syncthreads();

        const unsigned short* hread = hb + (size_t)(ls & 1) * BATCH * HD;
        f32x4 ar = {0.f,0.f,0.f,0.f}, az = {0.f,0.f,0.f,0.f}, an = {0.f,0.f,0.f,0.f};
        #pragma unroll
        for (int kk = 0; kk < 16; ++kk) {
            const bf16x8 af  = *(const bf16x8*)(hread + (size_t)arow * HD + kk * 32 + quad * 8);
            const bf16x8 br  = *(const bf16x8*)(&wlds[( 0 + jj) * 520 + kk * 32 + quad * 8]);
            const bf16x8 bz  = *(const bf16x8*)(&wlds[(16 + jj) * 520 + kk * 32 + quad * 8]);
            const bf16x8 bn_ = *(const bf16x8*)(&wlds[(32 + jj) * 520 + kk * 32 + quad * 8]);
            ar = __builtin_amdgcn_mfma_f32_16x16x32_bf16(af, br,  ar, 0, 0, 0);
            az = __builtin_amdgcn_mfma_f32_16x16x32_bf16(af, bz,  az, 0, 0, 0);
            an = __builtin_amdgcn_mfma_f32_16x16x32_bf16(af, bn_, an, 0, 0, 0);
        }

        float hnv[4];
        #pragma unroll
        for (int i = 0; i < 4; i++) {
            const float r = fsig(bf2f(gr[i]) + ar[i] + bh_r);
            const float z = fsig(bf2f(gz[i]) + az[i] + bh_z);
            const float n = ftanh(bf2f(gn[i]) + r * (an[i] + bh_n));
            hnv[i] = (1.f - z) * n + z * hown[i];
            hown[i] = hnv[i];
        }
        unsigned short* hwrite = hb + (size_t)((ls + 1) & 1) * BATCH * HD;
        #pragma unroll
        for (int i = 0; i < 4; i++) {
            hwrite[(size_t)(bb + i) * HD + j] = f2bf(hnv[i]);
            dst[((size_t)t * BATCH + bb + i) * 1024 + dir * HD + j] = stoT<DT>(hnv[i]);
        }
        __syncthreads();
        if (tid == 0) {
            __builtin_amdgcn_fence(__ATOMIC_RELEASE, "agent");
            __hip_atomic_fetch_add(cc, 1u, __ATOMIC_RELAXED, __HIP_MEMORY_SCOPE_AGENT);
        }
    }

    #pragma unroll
    for (int i = 0; i < 4; i++) hfd[(size_t)(bb + i) * HD + j] = hown[i];
    if (c == nc - 1) {
        float* find = finals + (size_t)dir * BATCH * HD;
        #pragma unroll
        for (int i = 0; i < 4; i++) find[(size_t)(bb + i) * HD + j] = hown[i];
    }
}

// ---------------------------------------------------------------------------
extern "C" void kernel_launch(void* const* d_in, const int* in_sizes, int n_in,
                              void* d_out, int out_size, void* d_ws, size_t ws_size,
                              hipStream_t stream)
{
    (void)in_sizes; (void)n_in; (void)out_size;

    const float* x  = (const float*)d_in[0];
    const float* h0 = (const float*)d_in[1];
    auto P = [&](int l, int k) { return (const float*)d_in[2 + l * 8 + k]; };
    // k: 0 wih, 1 whh, 2 bih, 3 bhh, 4 wihr, 5 whhr, 6 bihr, 7 bhhr

    const size_t OUTE = (size_t)T_SEQ * BATCH * 1024;   // sequence elems

    // pick largest chunk TC whose footprint fits ws_size (floor TC=8)
    int TC = 256;
    for (;;) {
        const size_t cntB = (size_t)3 * (T_SEQ / TC) * 128 * 4;
        const size_t giB  = (size_t)2 * TC * G3 * BATCH * 2;
        const size_t need = 262144 + cntB + giB + OUTE * 2;  // hbuf+hf32, cnt, gi, act1(bf16)
        if (need <= ws_size || TC == 8) break;
        TC >>= 1;
    }
    const int NC = T_SEQ / TC;
    const size_t cntB = (size_t)3 * NC * 128 * 4;

    unsigned char* w = (unsigned char*)d_ws;
    unsigned short* hbuf = (unsigned short*)w;                     // 131072 B
    float*          hf32 = (float*)(w + 131072);                   // 131072 B
    unsigned int*   cnts = (unsigned int*)(w + 262144);            // cntB
    unsigned short* gi   = (unsigned short*)(w + 262144 + cntB);
    unsigned short* act1 = gi + (size_t)2 * TC * G3 * BATCH;       // OUTE bf16

    float* out0f = (float*)d_out;                 // fp32 output 0 [T][B][1024]
    float* finf  = out0f + OUTE;                  // fp32 output 1 [6][32][512]
    unsigned short* act0 = (unsigned short*)d_out; // l0 bf16 scratch (first half
                                                   // of out0 bytes; consumed by
                                                   // l1 GEMM before l2 scan
                                                   // rewrites out0 as fp32)

    hipMemsetAsync(cnts, 0, cntB, stream);

    for (int l = 0; l < 3; ++l) {
        const int K = (l == 0) ? 256 : 1024;
        float* finl = finf + (size_t)l * 2 * BATCH * HD;
        const float* h0l = h0 + (size_t)l * 2 * BATCH * HD;

        for (int c = 0; c < NC; ++c) {
            const int rowBase0 = c * TC * 32;
            const int rowBase1 = (T_SEQ - (c + 1) * TC) * 32;
            const dim3 ggrid(12, (TC * 32) / 128, 2);

            if (l == 0) {
                gi_gemm<float><<<ggrid, 256, 0, stream>>>(
                    x, K, rowBase0, rowBase1,
                    P(l,0), P(l,4), P(l,2), P(l,6), gi, TC);
            } else {
                const unsigned short* actIn = (l == 1) ? act0 : act1;
                gi_gemm<unsigned short><<<ggrid, 256, 0, stream>>>(
                    actIn, K, rowBase0, rowBase1,
                    P(l,0), P(l,4), P(l,2), P(l,6), gi, TC);
            }

            unsigned int* cntp = cnts + (size_t)(l * NC + c) * 128;
            if (l == 0) {
                gru_scan<unsigned short><<<dim3(64), 128, 0, stream>>>(
                    gi, P(l,1), P(l,5), P(l,3), P(l,7), h0l,
                    act0, finl, hbuf, hf32, cntp, c, TC, NC);
            } else if (l == 1) {
                gru_scan<unsigned short><<<dim3(64), 128, 0, stream>>>(
                    gi, P(l,1), P(l,5), P(l,3), P(l,7), h0l,
                    act1, finl, hbuf, hf32, cntp, c, TC, NC);
            } else {
                gru_scan<float><<<dim3(64), 128, 0, stream>>>(
                    gi, P(l,1), P(l,5), P(l,3), P(l,7), h0l,
                    out0f, finl, hbuf, hf32, cntp, c, TC, NC);
            }
        }
    }
}